// Round 1
// baseline (3504.697 us; speedup 1.0000x reference)
//
#include <hip/hip_runtime.h>

#define BLK 256

typedef __bf16 bf16;
typedef __bf16 bf16x8 __attribute__((ext_vector_type(8)));
typedef float f32x4 __attribute__((ext_vector_type(4)));

__device__ __forceinline__ float sigm(float x) { return 1.f / (1.f + __expf(-x)); }
__device__ __forceinline__ float tanh_(float x) {
    x = fminf(fmaxf(x, -15.f), 15.f);
    float e = __expf(2.f * x);
    return (e - 1.f) / (e + 1.f);
}

// ---------------- small prep kernels ----------------

__global__ void k_cast(const float* __restrict__ in, bf16* __restrict__ out, int n) {
    int i = blockIdx.x * BLK + threadIdx.x;
    if (i < n) out[i] = (bf16)in[i];
}

__global__ void k_cast2(const float* __restrict__ in, bf16* __restrict__ hi,
                        bf16* __restrict__ lo, int n) {
    int i = blockIdx.x * BLK + threadIdx.x;
    if (i < n) {
        float v = in[i];
        bf16 h = (bf16)v;
        hi[i] = h;
        lo[i] = (bf16)(v - (float)h);
    }
}

// out[c][r] = in[r][c]; in is [512][C]; out is [C][512]. id = c*512 + r.
__global__ void k_tcast2(const float* __restrict__ in, bf16* __restrict__ hi,
                         bf16* __restrict__ lo, int C) {
    int id = blockIdx.x * BLK + threadIdx.x;
    int c = id >> 9, r = id & 511;
    float v = in[(size_t)r * C + c];
    bf16 h = (bf16)v;
    hi[id] = h;
    if (lo) lo[id] = (bf16)(v - (float)h);
}

// bz[c] = b_H2h @ W_rec + b_lstm
__global__ void k_bz(const float* __restrict__ bh, const float* __restrict__ Wr,
                     const float* __restrict__ bl, float* __restrict__ bz) {
    int c = blockIdx.x * BLK + threadIdx.x;  // 0..2047
    float s = bl[c];
    for (int k = 0; k < 512; k++) s += bh[k] * Wr[(size_t)k * 2048 + c];
    bz[c] = s;
}

// ---------------- P-matrix builder GEMM ----------------
// G[c][n'] = sum_k Wrec_t[c][k] * WH[n'][k]  (== WHW^T), M=2048, N=1024, K=512,
// split-bf16 3-pass (hi*hi + lo*hi + hi*lo) for ~fp32 product accuracy.
// Epilogue: P4/P1 (n'<512), P3/P5 (n'>=512), all [2048][512] bf16 K-contiguous.
__global__ __launch_bounds__(256, 2) void k_gemmP(
    const bf16* __restrict__ Ahi, const bf16* __restrict__ Alo,
    const bf16* __restrict__ Bhi, const bf16* __restrict__ Blo,
    const float* __restrict__ Wk,
    bf16* __restrict__ P1, bf16* __restrict__ P3,
    bf16* __restrict__ P4, bf16* __restrict__ P5) {
    __shared__ __align__(16) bf16 At[64 * 72];
    __shared__ __align__(16) bf16 Bt[4 * 64 * 72];
    const int t = threadIdx.x, w = t >> 6, l = t & 63;
    const int m0 = (blockIdx.x >> 2) * 64, n0 = (blockIdx.x & 3) * 256;
    f32x4 acc[4][4] = {};
    const bf16* Aps[3] = {Ahi, Alo, Ahi};
    const bf16* Bps[3] = {Bhi, Bhi, Blo};
    for (int p = 0; p < 3; p++) {
        const bf16* Ap = Aps[p] + (size_t)m0 * 512;
        const bf16* Bp = Bps[p];
        for (int kt = 0; kt < 8; kt++) {
            int k0 = kt * 64;
            __syncthreads();
#pragma unroll
            for (int q = 0; q < 2; q++) {
                int idx = q * 256 + t, row = idx >> 3, cc = idx & 7;
                uint4 v = *(const uint4*)(Ap + (size_t)row * 512 + k0 + cc * 8);
                *(uint4*)&At[row * 72 + cc * 8] = v;
            }
#pragma unroll
            for (int q = 0; q < 8; q++) {
                int idx = q * 256 + t, g = idx >> 9, rr = (idx >> 3) & 63, cc = idx & 7;
                uint4 v = *(const uint4*)(Bp + (size_t)(n0 + g * 64 + rr) * 512 + k0 + cc * 8);
                *(uint4*)&Bt[(g * 64 + rr) * 72 + cc * 8] = v;
            }
            __syncthreads();
#pragma unroll
            for (int ks = 0; ks < 2; ks++) {
                int ko = ks * 32 + (l >> 4) * 8;
                bf16x8 af[4], bb[4];
#pragma unroll
                for (int mt = 0; mt < 4; mt++)
                    af[mt] = *(const bf16x8*)&At[(mt * 16 + (l & 15)) * 72 + ko];
#pragma unroll
                for (int g = 0; g < 4; g++)
                    bb[g] = *(const bf16x8*)&Bt[(g * 64 + w * 16 + (l & 15)) * 72 + ko];
#pragma unroll
                for (int mt = 0; mt < 4; mt++)
#pragma unroll
                    for (int g = 0; g < 4; g++)
                        acc[mt][g] = __builtin_amdgcn_mfma_f32_16x16x32_bf16(
                            af[mt], bb[g], acc[mt][g], 0, 0, 0);
            }
        }
    }
    const bool hihalf = (n0 >= 512);
#pragma unroll
    for (int mt = 0; mt < 4; mt++) {
#pragma unroll
        for (int g = 0; g < 4; g++) {
            int np = n0 + g * 64 + w * 16 + (l & 15);
#pragma unroll
            for (int r = 0; r < 4; r++) {
                int c = m0 + mt * 16 + ((l >> 4) << 2) + r;
                float v = acc[mt][g][r];
                if (!hihalf) {
                    P4[(size_t)c * 512 + np] = (bf16)v;
                    P1[(size_t)c * 512 + np] = (bf16)(v + Wk[(size_t)np * 2048 + c]);
                } else {
                    int kk = np - 512;
                    P3[(size_t)c * 512 + kk] = (bf16)v;
                    P5[(size_t)c * 512 + kk] = (bf16)(v + Wk[(size_t)kk * 2048 + c]);
                }
            }
        }
    }
}

// ---------------- per-diagonal fused GEMM + LSTM gates ----------------
// grid = Kd*16 blocks; block: cell = bid>>4, sub = bid&15 -> side (z_s/z_t), 64-channel strip.
// C-tile 64(batch) x 256(4 gates x 64 ch). K halves selected per boundary type.
__global__ __launch_bounds__(256, 2) void k_diag(
    int d, int i_lo,
    const bf16* __restrict__ srcb, const bf16* __restrict__ tgtb,
    const bf16* __restrict__ P1, const bf16* __restrict__ P2,
    const bf16* __restrict__ P3, const bf16* __restrict__ P4,
    const bf16* __restrict__ P5,
    const float* __restrict__ bz,
    const bf16* __restrict__ shR, bf16* __restrict__ shW,
    const bf16* __restrict__ thR, bf16* __restrict__ thW,
    float* __restrict__ sc, float* __restrict__ tc,
    float* __restrict__ out) {
    __shared__ __align__(16) bf16 At[64 * 72];
    __shared__ __align__(16) bf16 Bt[4 * 64 * 72];
    const int t = threadIdx.x, w = t >> 6, l = t & 63;
    const int cell = blockIdx.x >> 4, sub = blockIdx.x & 15;
    const int side = sub >> 3, ch0 = (sub & 7) << 6;
    const int i = i_lo + cell, j = d - i;
    const size_t stI = (size_t)i * 64 * 512, stJ = (size_t)j * 64 * 512;

    const bf16* Ah[2];
    const bf16* Wh[2];
    int nh = 0;
    if (side == 0) {  // z_s
        Ah[nh] = (j == 0 ? srcb : shR) + stI;
        Wh[nh] = (j == 0 ? P2 : P1);
        nh++;
        if (i > 0) { Ah[nh] = thR + stJ; Wh[nh] = P3; nh++; }
    } else {  // z_t
        if (j > 0) { Ah[nh] = shR + stI; Wh[nh] = P4; nh++; }
        Ah[nh] = (i == 0 ? tgtb : thR) + stJ;
        Wh[nh] = (i == 0 ? P2 : P5);
        nh++;
    }

    f32x4 acc[4][4] = {};
    for (int hh = 0; hh < nh; hh++) {
        const bf16* Ap = Ah[hh];
        const bf16* Wp = Wh[hh];
        for (int kt = 0; kt < 8; kt++) {
            int k0 = kt * 64;
            __syncthreads();
#pragma unroll
            for (int q = 0; q < 2; q++) {
                int idx = q * 256 + t, row = idx >> 3, cc = idx & 7;
                uint4 v = *(const uint4*)(Ap + (size_t)row * 512 + k0 + cc * 8);
                *(uint4*)&At[row * 72 + cc * 8] = v;
            }
#pragma unroll
            for (int q = 0; q < 8; q++) {
                int idx = q * 256 + t, g = idx >> 9, rr = (idx >> 3) & 63, cc = idx & 7;
                uint4 v = *(const uint4*)(Wp + (size_t)(g * 512 + ch0 + rr) * 512 + k0 + cc * 8);
                *(uint4*)&Bt[(g * 64 + rr) * 72 + cc * 8] = v;
            }
            __syncthreads();
#pragma unroll
            for (int ks = 0; ks < 2; ks++) {
                int ko = ks * 32 + (l >> 4) * 8;
                bf16x8 af[4], bb[4];
#pragma unroll
                for (int mt = 0; mt < 4; mt++)
                    af[mt] = *(const bf16x8*)&At[(mt * 16 + (l & 15)) * 72 + ko];
#pragma unroll
                for (int g = 0; g < 4; g++)
                    bb[g] = *(const bf16x8*)&Bt[(g * 64 + w * 16 + (l & 15)) * 72 + ko];
#pragma unroll
                for (int mt = 0; mt < 4; mt++)
#pragma unroll
                    for (int g = 0; g < 4; g++)
                        acc[mt][g] = __builtin_amdgcn_mfma_f32_16x16x32_bf16(
                            af[mt], bb[g], acc[mt][g], 0, 0, 0);
            }
        }
    }

    // in-register gate epilogue: lane holds all 4 gates (strips) of its (b,h)
    const int h = ch0 + w * 16 + (l & 15);
    float bzv[4];
#pragma unroll
    for (int g = 0; g < 4; g++) bzv[g] = bz[g * 512 + h];
#pragma unroll
    for (int mt = 0; mt < 4; mt++) {
#pragma unroll
        for (int r = 0; r < 4; r++) {
            int b = mt * 16 + ((l >> 4) << 2) + r;
            float zi = acc[mt][0][r] + bzv[0];
            float zf = acc[mt][1][r] + bzv[1];
            float zg = acc[mt][2][r] + bzv[2];
            float zo = acc[mt][3][r] + bzv[3];
            if (side == 0) {
                size_t off = stI + (size_t)b * 512 + h;
                float cold = (j == 0) ? 0.f : sc[off];
                float c2 = sigm(zf) * cold + sigm(zi) * tanh_(zg);
                float h2 = sigm(zo) * tanh_(c2);
                sc[off] = c2;
                shW[off] = (bf16)h2;
                if (j == 31) out[off] = h2;  // source_out[i]
            } else {
                size_t off = stJ + (size_t)b * 512 + h;
                float cold = (i == 0) ? 0.f : tc[off];
                float c2 = sigm(zf) * cold + sigm(zi) * tanh_(zg);
                float h2 = sigm(zo) * tanh_(c2);
                tc[off] = c2;
                thW[off] = (bf16)h2;
                if (i == 31) out[1048576 + off] = h2;  // t_final[0][j]
            }
        }
    }
}

// ---------------- host ----------------

extern "C" void kernel_launch(void* const* d_in, const int* in_sizes, int n_in,
                              void* d_out, int out_size, void* d_ws, size_t ws_size,
                              hipStream_t stream) {
    const float* src = (const float*)d_in[0];
    const float* tgt = (const float*)d_in[1];
    const float* WH = (const float*)d_in[2];
    const float* bH = (const float*)d_in[3];
    const float* Wk = (const float*)d_in[4];
    const float* Wr = (const float*)d_in[5];
    const float* bl = (const float*)d_in[6];
    float* out = (float*)d_out;
    char* w = (char*)d_ws;
    const size_t MB = 1u << 20;
    bf16* srcb = (bf16*)(w + 0 * MB);    // [32][64][512]
    bf16* tgtb = (bf16*)(w + 2 * MB);
    bf16* WHhi = (bf16*)(w + 4 * MB);    // [1024][512]
    bf16* WHlo = (bf16*)(w + 5 * MB);
    bf16* Wrhi = (bf16*)(w + 6 * MB);    // [2048][512] (W_rec^T)
    bf16* Wrlo = (bf16*)(w + 8 * MB);
    bf16* P1 = (bf16*)(w + 10 * MB);     // Wk^T + WHW_hi^T
    bf16* P2 = (bf16*)(w + 12 * MB);     // Wk^T
    bf16* P3 = (bf16*)(w + 14 * MB);     // WHW_lo^T
    bf16* P4 = (bf16*)(w + 16 * MB);     // WHW_hi^T
    bf16* P5 = (bf16*)(w + 18 * MB);     // Wk^T + WHW_lo^T
    float* bz = (float*)(w + 20 * MB);   // [2048]
    bf16* sh = (bf16*)(w + 21 * MB);     // [2][32][64][512] double-buffered
    bf16* th = (bf16*)(w + 25 * MB);
    float* sc = (float*)(w + 29 * MB);   // [32][64][512] fp32
    float* tc = (float*)(w + 33 * MB);   // end: 37 MB

    k_cast<<<4096, BLK, 0, stream>>>(src, srcb, 1048576);
    k_cast<<<4096, BLK, 0, stream>>>(tgt, tgtb, 1048576);
    k_cast2<<<2048, BLK, 0, stream>>>(WH, WHhi, WHlo, 524288);
    k_tcast2<<<4096, BLK, 0, stream>>>(Wr, Wrhi, Wrlo, 2048);
    k_tcast2<<<4096, BLK, 0, stream>>>(Wk, P2, nullptr, 2048);
    k_bz<<<8, BLK, 0, stream>>>(bH, Wr, bl, bz);
    k_gemmP<<<128, BLK, 0, stream>>>(Wrhi, Wrlo, WHhi, WHlo, Wk, P1, P3, P4, P5);

    for (int d = 0; d < 63; d++) {
        int i_lo = d > 31 ? d - 31 : 0;
        int i_hi = d < 31 ? d : 31;
        int Kd = i_hi - i_lo + 1;
        const bf16* shR = sh + (size_t)(d & 1) * 1048576;
        bf16* shW = sh + (size_t)((d + 1) & 1) * 1048576;
        const bf16* thR = th + (size_t)(d & 1) * 1048576;
        bf16* thW = th + (size_t)((d + 1) & 1) * 1048576;
        k_diag<<<Kd * 16, BLK, 0, stream>>>(d, i_lo, srcb, tgtb, P1, P2, P3, P4, P5,
                                            bz, shR, shW, thR, thW, sc, tc, out);
    }
}

// Round 2
// 1467.393 us; speedup vs baseline: 2.3884x; 2.3884x over previous
//
#include <hip/hip_runtime.h>

#define BLK 256

typedef __bf16 bf16;
typedef __bf16 bf16x8 __attribute__((ext_vector_type(8)));
typedef float f32x4 __attribute__((ext_vector_type(4)));

__device__ __forceinline__ float sigm(float x) { return 1.f / (1.f + __expf(-x)); }
__device__ __forceinline__ float tanh_(float x) {
    x = fminf(fmaxf(x, -15.f), 15.f);
    float e = __expf(2.f * x);
    return (e - 1.f) / (e + 1.f);
}

// async 16B global->LDS; lds dest must be wave-uniform base (lane*16 implicit)
__device__ __forceinline__ void gl2lds(const bf16* g, bf16* l) {
    __builtin_amdgcn_global_load_lds((const __attribute__((address_space(1))) void*)g,
                                     (__attribute__((address_space(3))) void*)l, 16, 0, 0);
}

// ---------------- small prep kernels ----------------

__global__ void k_cast(const float* __restrict__ in, bf16* __restrict__ out, int n) {
    int i = blockIdx.x * BLK + threadIdx.x;
    if (i < n) out[i] = (bf16)in[i];
}

__global__ void k_cast2(const float* __restrict__ in, bf16* __restrict__ hi,
                        bf16* __restrict__ lo, int n) {
    int i = blockIdx.x * BLK + threadIdx.x;
    if (i < n) {
        float v = in[i];
        bf16 h = (bf16)v;
        hi[i] = h;
        lo[i] = (bf16)(v - (float)h);
    }
}

// out[c][r] = in[r][c]; in is [512][C]; out is [C][512]. id = c*512 + r.
__global__ void k_tcast2(const float* __restrict__ in, bf16* __restrict__ hi,
                         bf16* __restrict__ lo, int C) {
    int id = blockIdx.x * BLK + threadIdx.x;
    int c = id >> 9, r = id & 511;
    float v = in[(size_t)r * C + c];
    bf16 h = (bf16)v;
    hi[id] = h;
    if (lo) lo[id] = (bf16)(v - (float)h);
}

// bz[c] = b_H2h @ W_rec + b_lstm
__global__ void k_bz(const float* __restrict__ bh, const float* __restrict__ Wr,
                     const float* __restrict__ bl, float* __restrict__ bz) {
    int c = blockIdx.x * BLK + threadIdx.x;  // 0..2047
    float s = bl[c];
    for (int k = 0; k < 512; k++) s += bh[k] * Wr[(size_t)k * 2048 + c];
    bz[c] = s;
}

// ---------------- P-matrix builder GEMM (runs once, ~1% of time) ----------------
__global__ __launch_bounds__(256, 2) void k_gemmP(
    const bf16* __restrict__ Ahi, const bf16* __restrict__ Alo,
    const bf16* __restrict__ Bhi, const bf16* __restrict__ Blo,
    const float* __restrict__ Wk,
    bf16* __restrict__ P1, bf16* __restrict__ P3,
    bf16* __restrict__ P4, bf16* __restrict__ P5) {
    __shared__ __align__(16) bf16 At[64 * 72];
    __shared__ __align__(16) bf16 Bt[4 * 64 * 72];
    const int t = threadIdx.x, w = t >> 6, l = t & 63;
    const int m0 = (blockIdx.x >> 2) * 64, n0 = (blockIdx.x & 3) * 256;
    f32x4 acc[4][4] = {};
    const bf16* Aps[3] = {Ahi, Alo, Ahi};
    const bf16* Bps[3] = {Bhi, Bhi, Blo};
    for (int p = 0; p < 3; p++) {
        const bf16* Ap = Aps[p] + (size_t)m0 * 512;
        const bf16* Bp = Bps[p];
        for (int kt = 0; kt < 8; kt++) {
            int k0 = kt * 64;
            __syncthreads();
#pragma unroll
            for (int q = 0; q < 2; q++) {
                int idx = q * 256 + t, row = idx >> 3, cc = idx & 7;
                uint4 v = *(const uint4*)(Ap + (size_t)row * 512 + k0 + cc * 8);
                *(uint4*)&At[row * 72 + cc * 8] = v;
            }
#pragma unroll
            for (int q = 0; q < 8; q++) {
                int idx = q * 256 + t, g = idx >> 9, rr = (idx >> 3) & 63, cc = idx & 7;
                uint4 v = *(const uint4*)(Bp + (size_t)(n0 + g * 64 + rr) * 512 + k0 + cc * 8);
                *(uint4*)&Bt[(g * 64 + rr) * 72 + cc * 8] = v;
            }
            __syncthreads();
#pragma unroll
            for (int ks = 0; ks < 2; ks++) {
                int ko = ks * 32 + (l >> 4) * 8;
                bf16x8 af[4], bb[4];
#pragma unroll
                for (int mt = 0; mt < 4; mt++)
                    af[mt] = *(const bf16x8*)&At[(mt * 16 + (l & 15)) * 72 + ko];
#pragma unroll
                for (int g = 0; g < 4; g++)
                    bb[g] = *(const bf16x8*)&Bt[(g * 64 + w * 16 + (l & 15)) * 72 + ko];
#pragma unroll
                for (int mt = 0; mt < 4; mt++)
#pragma unroll
                    for (int g = 0; g < 4; g++)
                        acc[mt][g] = __builtin_amdgcn_mfma_f32_16x16x32_bf16(
                            af[mt], bb[g], acc[mt][g], 0, 0, 0);
            }
        }
    }
    const bool hihalf = (n0 >= 512);
#pragma unroll
    for (int mt = 0; mt < 4; mt++) {
#pragma unroll
        for (int g = 0; g < 4; g++) {
            int np = n0 + g * 64 + w * 16 + (l & 15);
#pragma unroll
            for (int r = 0; r < 4; r++) {
                int c = m0 + mt * 16 + ((l >> 4) << 2) + r;
                float v = acc[mt][g][r];
                if (!hihalf) {
                    P4[(size_t)c * 512 + np] = (bf16)v;
                    P1[(size_t)c * 512 + np] = (bf16)(v + Wk[(size_t)np * 2048 + c]);
                } else {
                    int kk = np - 512;
                    P3[(size_t)c * 512 + kk] = (bf16)v;
                    P5[(size_t)c * 512 + kk] = (bf16)(v + Wk[(size_t)kk * 2048 + c]);
                }
            }
        }
    }
}

// ---------------- per-diagonal fused GEMM + LSTM gates ----------------
// grid = Kd*32; sub = bid&31: side = sub>>4, strip = sub&15 (32 channels).
// C-tile 64(batch) x 128(4 gates x 32 ch). global_load_lds staging with
// 16B-granule XOR swizzle (c ^= r&7) -> ds_read_b128 conflict-free unpadded.
__global__ __launch_bounds__(256, 4) void k_diag(
    int d, int i_lo,
    const bf16* __restrict__ srcb, const bf16* __restrict__ tgtb,
    const bf16* __restrict__ P1, const bf16* __restrict__ P2,
    const bf16* __restrict__ P3, const bf16* __restrict__ P4,
    const bf16* __restrict__ P5,
    const float* __restrict__ bz,
    const bf16* __restrict__ shR, bf16* __restrict__ shW,
    const bf16* __restrict__ thR, bf16* __restrict__ thW,
    float* __restrict__ sc, float* __restrict__ tc,
    float* __restrict__ out) {
    __shared__ __align__(16) bf16 At[64 * 64];   // 8 KB, swizzled
    __shared__ __align__(16) bf16 Bt[128 * 64];  // 16 KB, swizzled
    const int t = threadIdx.x, w = t >> 6, l = t & 63;
    const int cell = blockIdx.x >> 5, sub = blockIdx.x & 31;
    const int side = sub >> 4, ch0 = (sub & 15) << 5;
    const int i = i_lo + cell, j = d - i;
    const size_t stI = (size_t)i * 64 * 512, stJ = (size_t)j * 64 * 512;

    const bf16* Ah[2];
    const bf16* Wh[2];
    int nh = 0;
    if (side == 0) {  // z_s
        Ah[nh] = (j == 0 ? srcb : shR) + stI;
        Wh[nh] = (j == 0 ? P2 : P1);
        nh++;
        if (i > 0) { Ah[nh] = thR + stJ; Wh[nh] = P3; nh++; }
    } else {  // z_t
        if (j > 0) { Ah[nh] = shR + stI; Wh[nh] = P4; nh++; }
        Ah[nh] = (i == 0 ? tgtb : thR) + stJ;
        Wh[nh] = (i == 0 ? P2 : P5);
        nh++;
    }

    f32x4 acc[2][4] = {};
    for (int hh = 0; hh < nh; hh++) {
        const bf16* Ap = Ah[hh];
        const bf16* Wp = Wh[hh];
        for (int kt = 0; kt < 8; kt++) {
            int k0 = kt * 64;
            __syncthreads();
            // A tile: 64 rows x 64 K = 512 x 16B chunks, 2 rounds
#pragma unroll
            for (int q = 0; q < 2; q++) {
                int p = q * 256 + t;
                int r = p >> 3, c = (p & 7) ^ (r & 7);
                gl2lds(Ap + (size_t)r * 512 + k0 + c * 8, &At[(q * 256 + w * 64) * 8]);
            }
            // B tile: 128 rows (4 gates x 32 ch) x 64 K = 1024 chunks, 4 rounds
#pragma unroll
            for (int q = 0; q < 4; q++) {
                int p = q * 256 + t;
                int r = p >> 3, c = (p & 7) ^ (r & 7);
                int g = r >> 5;
                gl2lds(Wp + (size_t)(g * 512 + ch0 + (r & 31)) * 512 + k0 + c * 8,
                       &Bt[(q * 256 + w * 64) * 8]);
            }
            __syncthreads();
#pragma unroll
            for (int ks = 0; ks < 2; ks++) {
                int c = ks * 4 + (l >> 4);
                bf16x8 af[2], bb[4];
#pragma unroll
                for (int mt = 0; mt < 2; mt++) {
                    int r = (w >> 1) * 32 + mt * 16 + (l & 15);
                    af[mt] = *(const bf16x8*)&At[(r * 8 + (c ^ (r & 7))) * 8];
                }
#pragma unroll
                for (int g = 0; g < 4; g++) {
                    int r = g * 32 + (w & 1) * 16 + (l & 15);
                    bb[g] = *(const bf16x8*)&Bt[(r * 8 + (c ^ (r & 7))) * 8];
                }
#pragma unroll
                for (int mt = 0; mt < 2; mt++)
#pragma unroll
                    for (int g = 0; g < 4; g++)
                        acc[mt][g] = __builtin_amdgcn_mfma_f32_16x16x32_bf16(
                            af[mt], bb[g], acc[mt][g], 0, 0, 0);
            }
        }
    }

    // in-register gate epilogue: lane holds all 4 gates of its (b, h)
    const int h = ch0 + (w & 1) * 16 + (l & 15);
    float bzv[4];
#pragma unroll
    for (int g = 0; g < 4; g++) bzv[g] = bz[g * 512 + h];
#pragma unroll
    for (int mt = 0; mt < 2; mt++) {
#pragma unroll
        for (int r = 0; r < 4; r++) {
            int b = (w >> 1) * 32 + mt * 16 + ((l >> 4) << 2) + r;
            float zi = acc[mt][0][r] + bzv[0];
            float zf = acc[mt][1][r] + bzv[1];
            float zg = acc[mt][2][r] + bzv[2];
            float zo = acc[mt][3][r] + bzv[3];
            if (side == 0) {
                size_t off = stI + (size_t)b * 512 + h;
                float cold = (j == 0) ? 0.f : sc[off];
                float c2 = sigm(zf) * cold + sigm(zi) * tanh_(zg);
                float h2 = sigm(zo) * tanh_(c2);
                sc[off] = c2;
                shW[off] = (bf16)h2;
                if (j == 31) out[off] = h2;  // source_out[i]
            } else {
                size_t off = stJ + (size_t)b * 512 + h;
                float cold = (i == 0) ? 0.f : tc[off];
                float c2 = sigm(zf) * cold + sigm(zi) * tanh_(zg);
                float h2 = sigm(zo) * tanh_(c2);
                tc[off] = c2;
                thW[off] = (bf16)h2;
                if (i == 31) out[1048576 + off] = h2;  // t_final[0][j]
            }
        }
    }
}

// ---------------- host ----------------

extern "C" void kernel_launch(void* const* d_in, const int* in_sizes, int n_in,
                              void* d_out, int out_size, void* d_ws, size_t ws_size,
                              hipStream_t stream) {
    const float* src = (const float*)d_in[0];
    const float* tgt = (const float*)d_in[1];
    const float* WH = (const float*)d_in[2];
    const float* bH = (const float*)d_in[3];
    const float* Wk = (const float*)d_in[4];
    const float* Wr = (const float*)d_in[5];
    const float* bl = (const float*)d_in[6];
    float* out = (float*)d_out;
    char* w = (char*)d_ws;
    const size_t MB = 1u << 20;
    bf16* srcb = (bf16*)(w + 0 * MB);    // [32][64][512]
    bf16* tgtb = (bf16*)(w + 2 * MB);
    bf16* WHhi = (bf16*)(w + 4 * MB);    // [1024][512]
    bf16* WHlo = (bf16*)(w + 5 * MB);
    bf16* Wrhi = (bf16*)(w + 6 * MB);    // [2048][512] (W_rec^T)
    bf16* Wrlo = (bf16*)(w + 8 * MB);
    bf16* P1 = (bf16*)(w + 10 * MB);     // Wk^T + WHW_hi^T
    bf16* P2 = (bf16*)(w + 12 * MB);     // Wk^T
    bf16* P3 = (bf16*)(w + 14 * MB);     // WHW_lo^T
    bf16* P4 = (bf16*)(w + 16 * MB);     // WHW_hi^T
    bf16* P5 = (bf16*)(w + 18 * MB);     // Wk^T + WHW_lo^T
    float* bz = (float*)(w + 20 * MB);   // [2048]
    bf16* sh = (bf16*)(w + 21 * MB);     // [2][32][64][512] double-buffered
    bf16* th = (bf16*)(w + 25 * MB);
    float* sc = (float*)(w + 29 * MB);   // [32][64][512] fp32
    float* tc = (float*)(w + 33 * MB);   // end: 37 MB

    k_cast<<<4096, BLK, 0, stream>>>(src, srcb, 1048576);
    k_cast<<<4096, BLK, 0, stream>>>(tgt, tgtb, 1048576);
    k_cast2<<<2048, BLK, 0, stream>>>(WH, WHhi, WHlo, 524288);
    k_tcast2<<<4096, BLK, 0, stream>>>(Wr, Wrhi, Wrlo, 2048);
    k_tcast2<<<4096, BLK, 0, stream>>>(Wk, P2, nullptr, 2048);
    k_bz<<<8, BLK, 0, stream>>>(bH, Wr, bl, bz);
    k_gemmP<<<128, BLK, 0, stream>>>(Wrhi, Wrlo, WHhi, WHlo, Wk, P1, P3, P4, P5);

    for (int d = 0; d < 63; d++) {
        int i_lo = d > 31 ? d - 31 : 0;
        int i_hi = d < 31 ? d : 31;
        int Kd = i_hi - i_lo + 1;
        const bf16* shR = sh + (size_t)(d & 1) * 1048576;
        bf16* shW = sh + (size_t)((d + 1) & 1) * 1048576;
        const bf16* thR = th + (size_t)(d & 1) * 1048576;
        bf16* thW = th + (size_t)((d + 1) & 1) * 1048576;
        k_diag<<<Kd * 32, BLK, 0, stream>>>(d, i_lo, srcb, tgtb, P1, P2, P3, P4, P5,
                                            bz, shR, shW, thR, thW, sc, tc, out);
    }
}